// Round 1
// baseline (186.602 us; speedup 1.0000x reference)
//
#include <hip/hip_runtime.h>

// Kalman filter scan: B=128, T=256, V=256. One thread per (b,v) track.
// State: s[4], symmetric P (10 unique elems). F=[[1,0,1,0],[0,1,0,1],[0,0,1,0],[0,0,0,1]],
// H = first two rows of I, Q=0.01*I, R=I, P0=1000*I, s0=0.
// Missing obs (label == -1): pure predict step. Implemented branchlessly by
// scaling idet (hence K) by mask m in {0,1}: K=0 => s_new=s_pred, P_new=P_pred.

#define KF_B 128
#define KF_T 256
#define KF_V 256

__global__ __launch_bounds__(64) void kf_kernel(const float* __restrict__ batch,
                                                float* __restrict__ out) {
    const int tid = blockIdx.x * 64 + threadIdx.x;   // 0 .. B*V-1
    const int b = tid >> 8;          // / V
    const int v = tid & (KF_V - 1);  // % V

    const float* __restrict__ ptr = batch + ((size_t)b * KF_T * KF_V + v) * 3;
    const int stride = KF_V * 3;     // 768 floats between consecutive t

    // state
    float s0 = 0.f, s1 = 0.f, s2 = 0.f, s3 = 0.f;
    float p00 = 1000.f, p01 = 0.f, p02 = 0.f, p03 = 0.f;
    float p11 = 1000.f, p12 = 0.f, p13 = 0.f;
    float p22 = 1000.f, p23 = 0.f;
    float p33 = 1000.f;

    const float Qd = 0.01f;

    // 4-step blocks, prefetch next block while computing current
    float cur[4][3];
#pragma unroll
    for (int k = 0; k < 4; ++k) {
        cur[k][0] = ptr[k * stride + 0];
        cur[k][1] = ptr[k * stride + 1];
        cur[k][2] = ptr[k * stride + 2];
    }
    ptr += 4 * stride;

    for (int g = 0; g < KF_T / 4; ++g) {
        float nxt[4][3];
        const bool have_next = (g < KF_T / 4 - 1);
        if (have_next) {
#pragma unroll
            for (int k = 0; k < 4; ++k) {
                nxt[k][0] = ptr[k * stride + 0];
                nxt[k][1] = ptr[k * stride + 1];
                nxt[k][2] = ptr[k * stride + 2];
            }
            ptr += 4 * stride;
        }

#pragma unroll
        for (int k = 0; k < 4; ++k) {
            const float label = cur[k][0];
            const float z0 = cur[k][1];
            const float z1 = cur[k][2];

            // ---- predict: s_pred = F s ; P_pred = F P F^T + Q ----
            const float sp0 = s0 + s2;
            const float sp1 = s1 + s3;
            const float sp2 = s2;
            const float sp3 = s3;

            const float q00 = p00 + 2.f * p02 + p22 + Qd;
            const float q01 = p01 + p12 + p03 + p23;
            const float q02 = p02 + p22;
            const float q03 = p03 + p23;
            const float q11 = p11 + 2.f * p13 + p33 + Qd;
            const float q12 = p12 + p23;
            const float q13 = p13 + p33;
            const float q22 = p22 + Qd;
            const float q23 = p23;
            const float q33 = p33 + Qd;

            // ---- innovation covariance S = P_pred[:2,:2] + R, inverse ----
            const float S00 = q00 + 1.f;
            const float S01 = q01;
            const float S11 = q11 + 1.f;
            const float det = S00 * S11 - S01 * S01;
            const float m = (label != -1.0f) ? 1.0f : 0.0f;
            const float idet = m * __builtin_amdgcn_rcpf(det);

            // ---- K = P_pred[:, :2] @ inv(S), pre-scaled by mask ----
            const float K00 = idet * (q00 * S11 - q01 * S01);
            const float K01 = idet * (q01 * S00 - q00 * S01);
            const float K10 = idet * (q01 * S11 - q11 * S01);
            const float K11 = idet * (q11 * S00 - q01 * S01);
            const float K20 = idet * (q02 * S11 - q12 * S01);
            const float K21 = idet * (q12 * S00 - q02 * S01);
            const float K30 = idet * (q03 * S11 - q13 * S01);
            const float K31 = idet * (q13 * S00 - q03 * S01);

            const float y0 = z0 - sp0;
            const float y1 = z1 - sp1;

            // ---- state update ----
            s0 = sp0 + K00 * y0 + K01 * y1;
            s1 = sp1 + K10 * y0 + K11 * y1;
            s2 = sp2 + K20 * y0 + K21 * y1;
            s3 = sp3 + K30 * y0 + K31 * y1;

            // ---- covariance update: P_new = P_pred - K @ P_pred[:2, :] ----
            p00 = q00 - (K00 * q00 + K01 * q01);
            p01 = q01 - (K00 * q01 + K01 * q11);
            p02 = q02 - (K00 * q02 + K01 * q12);
            p03 = q03 - (K00 * q03 + K01 * q13);
            p11 = q11 - (K10 * q01 + K11 * q11);
            p12 = q12 - (K10 * q02 + K11 * q12);
            p13 = q13 - (K10 * q03 + K11 * q13);
            p22 = q22 - (K20 * q02 + K21 * q12);
            p23 = q23 - (K20 * q03 + K21 * q13);
            p33 = q33 - (K30 * q03 + K31 * q13);
        }

        if (have_next) {
#pragma unroll
            for (int k = 0; k < 4; ++k) {
                cur[k][0] = nxt[k][0];
                cur[k][1] = nxt[k][1];
                cur[k][2] = nxt[k][2];
            }
        }
    }

    // ---- output: (1, s0, s1) per track ----
    float* o = out + (size_t)tid * 3;
    o[0] = 1.0f;
    o[1] = s0;
    o[2] = s1;
}

extern "C" void kernel_launch(void* const* d_in, const int* in_sizes, int n_in,
                              void* d_out, int out_size, void* d_ws, size_t ws_size,
                              hipStream_t stream) {
    (void)in_sizes; (void)n_in; (void)d_ws; (void)ws_size; (void)out_size;
    const float* batch = (const float*)d_in[0];
    float* out = (float*)d_out;
    const int total = KF_B * KF_V;            // 32768 threads
    kf_kernel<<<total / 64, 64, 0, stream>>>(batch, out);
}

// Round 2
// 168.671 us; speedup vs baseline: 1.1063x; 1.1063x over previous
//
#include <hip/hip_runtime.h>

// Kalman filter scan: B=128, T=256, V=256. One thread per (b,v) track.
// Latency-bound at 512 waves / 1024 SIMDs -> deep (8-step) ping-pong prefetch
// so HBM latency (~900 cyc) hides under ~1360 issue-cycles of compute.

#define KF_B 128
#define KF_T 256
#define KF_V 256
#define KF_G 8   // steps per prefetch group

__global__ __launch_bounds__(64) void kf_kernel(const float* __restrict__ batch,
                                                float* __restrict__ out) {
    const int tid = blockIdx.x * 64 + threadIdx.x;   // 0 .. B*V-1
    const int b = tid >> 8;          // / V
    const int v = tid & (KF_V - 1);  // % V

    const float* __restrict__ ptr = batch + ((size_t)b * KF_T * KF_V + v) * 3;
    const int stride = KF_V * 3;     // floats between consecutive t

    // state
    float s0 = 0.f, s1 = 0.f, s2 = 0.f, s3 = 0.f;
    float p00 = 1000.f, p01 = 0.f, p02 = 0.f, p03 = 0.f;
    float p11 = 1000.f, p12 = 0.f, p13 = 0.f;
    float p22 = 1000.f, p23 = 0.f;
    float p33 = 1000.f;

    const float Qd = 0.01f;

    float bufA[KF_G][3], bufB[KF_G][3];

#define KF_LOAD(dst)                               \
    do {                                           \
        _Pragma("unroll")                          \
        for (int k = 0; k < KF_G; ++k) {           \
            (dst)[k][0] = ptr[k * stride + 0];     \
            (dst)[k][1] = ptr[k * stride + 1];     \
            (dst)[k][2] = ptr[k * stride + 2];     \
        }                                          \
        ptr += KF_G * stride;                      \
    } while (0)

#define KF_STEP(obs)                                                        \
    do {                                                                    \
        const float label = (obs)[0];                                       \
        const float z0 = (obs)[1];                                          \
        const float z1 = (obs)[2];                                          \
        /* predict */                                                       \
        const float sp0 = s0 + s2;                                          \
        const float sp1 = s1 + s3;                                          \
        const float q00 = p00 + 2.f * p02 + p22 + Qd;                       \
        const float q01 = p01 + p12 + p03 + p23;                            \
        const float q02 = p02 + p22;                                        \
        const float q03 = p03 + p23;                                        \
        const float q11 = p11 + 2.f * p13 + p33 + Qd;                       \
        const float q12 = p12 + p23;                                        \
        const float q13 = p13 + p33;                                        \
        const float q22 = p22 + Qd;                                         \
        const float q23 = p23;                                              \
        const float q33 = p33 + Qd;                                         \
        /* innovation cov + masked inverse */                               \
        const float S00 = q00 + 1.f;                                        \
        const float S01 = q01;                                              \
        const float S11 = q11 + 1.f;                                        \
        const float det = S00 * S11 - S01 * S01;                            \
        const float m = (label != -1.0f) ? 1.0f : 0.0f;                     \
        const float idet = m * __builtin_amdgcn_rcpf(det);                  \
        const float t0 = idet * S11;                                        \
        const float t1 = idet * S01;                                        \
        const float t2 = idet * S00;                                        \
        const float K00 = q00 * t0 - q01 * t1;                              \
        const float K01 = q01 * t2 - q00 * t1;                              \
        const float K10 = q01 * t0 - q11 * t1;                              \
        const float K11 = q11 * t2 - q01 * t1;                              \
        const float K20 = q02 * t0 - q12 * t1;                              \
        const float K21 = q12 * t2 - q02 * t1;                              \
        const float K30 = q03 * t0 - q13 * t1;                              \
        const float K31 = q13 * t2 - q03 * t1;                              \
        const float y0 = z0 - sp0;                                          \
        const float y1 = z1 - sp1;                                          \
        s0 = sp0 + K00 * y0 + K01 * y1;                                     \
        s1 = sp1 + K10 * y0 + K11 * y1;                                     \
        /* s2,s3 unchanged by predict; add gain */                          \
        s2 = s2 + K20 * y0 + K21 * y1;                                      \
        s3 = s3 + K30 * y0 + K31 * y1;                                      \
        p00 = q00 - (K00 * q00 + K01 * q01);                                \
        p01 = q01 - (K00 * q01 + K01 * q11);                                \
        p02 = q02 - (K00 * q02 + K01 * q12);                                \
        p03 = q03 - (K00 * q03 + K01 * q13);                                \
        p11 = q11 - (K10 * q01 + K11 * q11);                                \
        p12 = q12 - (K10 * q02 + K11 * q12);                                \
        p13 = q13 - (K10 * q03 + K11 * q13);                                \
        p22 = q22 - (K20 * q02 + K21 * q12);                                \
        p23 = q23 - (K20 * q03 + K21 * q13);                                \
        p33 = q33 - (K30 * q03 + K31 * q13);                                \
    } while (0)

    // prologue: load group 0
    KF_LOAD(bufA);

    const int NG = KF_T / KF_G;   // 32 groups
    for (int g = 0; g < NG; g += 2) {
        // load group g+1 (always exists: g <= NG-2)
        KF_LOAD(bufB);
#pragma unroll
        for (int k = 0; k < KF_G; ++k) KF_STEP(bufA[k]);
        if (g + 2 < NG) {
            KF_LOAD(bufA);
        }
#pragma unroll
        for (int k = 0; k < KF_G; ++k) KF_STEP(bufB[k]);
    }

    // ---- output: (1, s0, s1) per track ----
    float* o = out + (size_t)tid * 3;
    o[0] = 1.0f;
    o[1] = s0;
    o[2] = s1;
}

extern "C" void kernel_launch(void* const* d_in, const int* in_sizes, int n_in,
                              void* d_out, int out_size, void* d_ws, size_t ws_size,
                              hipStream_t stream) {
    (void)in_sizes; (void)n_in; (void)d_ws; (void)ws_size; (void)out_size;
    const float* batch = (const float*)d_in[0];
    float* out = (float*)d_out;
    const int total = KF_B * KF_V;            // 32768 threads
    kf_kernel<<<total / 64, 64, 0, stream>>>(batch, out);
}

// Round 3
// 147.452 us; speedup vs baseline: 1.2655x; 1.1439x over previous
//
#include <hip/hip_runtime.h>

// Kalman filter scan: B=128, T=256, V=256. One thread per (b,v) track.
//
// KEY ALGEBRA: the 4D (x, y, vx, vy) filter decouples exactly into two
// independent 2D (pos, vel) filters, and the cross-covariance terms are
// EXACTLY zero in the reference's fp arithmetic (P0 diagonal, S exactly
// diagonal, inv(diag) has exact-zero off-diagonals). Furthermore P_x == P_y
// identically (same init, same mask, same Q/R), so ONE shared 2x2 Riccati
// recursion (p00, p01, p11; scalar S; scalar rcp) serves both axes.
// Step cost drops ~84 -> ~24 VALU instrs; kernel becomes memory-bound.

#define KF_B 128
#define KF_T 256
#define KF_V 256
#define KF_G 32   // steps per prefetch group (ping-pong)

__global__ __launch_bounds__(64) void kf_kernel(const float* __restrict__ batch,
                                                float* __restrict__ out) {
    const int tid = blockIdx.x * 64 + threadIdx.x;   // 0 .. B*V-1
    const int b = tid >> 8;          // / V
    const int v = tid & (KF_V - 1);  // % V

    const float* __restrict__ ptr = batch + ((size_t)b * KF_T * KF_V + v) * 3;
    const int stride = KF_V * 3;     // floats between consecutive t

    // shared 2x2 covariance (both axes identical), and per-axis states
    float p00 = 1000.f, p01 = 0.f, p11 = 1000.f;
    float x0 = 0.f, v0 = 0.f;   // axis 0: pos, vel
    float x1 = 0.f, v1 = 0.f;   // axis 1: pos, vel

    float bufA[KF_G][3], bufB[KF_G][3];

#define KF_LOAD(dst)                               \
    do {                                           \
        _Pragma("unroll")                          \
        for (int k = 0; k < KF_G; ++k) {           \
            (dst)[k][0] = ptr[k * stride + 0];     \
            (dst)[k][1] = ptr[k * stride + 1];     \
            (dst)[k][2] = ptr[k * stride + 2];     \
        }                                          \
        ptr += KF_G * stride;                      \
    } while (0)

#define KF_STEP(obs)                                                    \
    do {                                                                \
        const float label = (obs)[0];                                   \
        const float z0 = (obs)[1];                                      \
        const float z1 = (obs)[2];                                      \
        /* predict */                                                   \
        const float xp0 = x0 + v0;                                      \
        const float xp1 = x1 + v1;                                      \
        const float q00 = p00 + 2.f * p01 + p11 + 0.01f;                \
        const float q01 = p01 + p11;                                    \
        const float q11 = p11 + 0.01f;                                  \
        /* innovation variance (scalar!) + masked inverse */            \
        const float S = q00 + 1.f;                                      \
        const float m = (label != -1.0f) ? 1.0f : 0.0f;                 \
        const float is = m * __builtin_amdgcn_rcpf(S);                  \
        const float K0 = q00 * is;                                      \
        const float K1 = q01 * is;                                      \
        /* state update, both axes share K */                           \
        const float y0 = z0 - xp0;                                      \
        const float y1 = z1 - xp1;                                      \
        x0 = xp0 + K0 * y0;                                             \
        v0 = v0 + K1 * y0;                                              \
        x1 = xp1 + K0 * y1;                                             \
        v1 = v1 + K1 * y1;                                              \
        /* covariance update */                                         \
        p00 = q00 - K0 * q00;                                           \
        p01 = q01 - K0 * q01;                                           \
        p11 = q11 - K1 * q01;                                           \
    } while (0)

    // prologue: load group 0
    KF_LOAD(bufA);

    const int NG = KF_T / KF_G;   // 8 groups
    for (int g = 0; g < NG; g += 2) {
        KF_LOAD(bufB);
#pragma unroll
        for (int k = 0; k < KF_G; ++k) KF_STEP(bufA[k]);
        if (g + 2 < NG) {
            KF_LOAD(bufA);
        }
#pragma unroll
        for (int k = 0; k < KF_G; ++k) KF_STEP(bufB[k]);
    }

    // ---- output: (1, x, y) per track ----
    float* o = out + (size_t)tid * 3;
    o[0] = 1.0f;
    o[1] = x0;
    o[2] = x1;
}

extern "C" void kernel_launch(void* const* d_in, const int* in_sizes, int n_in,
                              void* d_out, int out_size, void* d_ws, size_t ws_size,
                              hipStream_t stream) {
    (void)in_sizes; (void)n_in; (void)d_ws; (void)ws_size; (void)out_size;
    const float* batch = (const float*)d_in[0];
    float* out = (float*)d_out;
    const int total = KF_B * KF_V;            // 32768 threads
    kf_kernel<<<total / 64, 64, 0, stream>>>(batch, out);
}